// Round 15
// baseline (193.042 us; speedup 1.0000x reference)
//
#include <hip/hip_runtime.h>
#include <hip/hip_bf16.h>

// 3D window attention (Swin-style), fully fused per 4x4x4 window.
// x:(2,64,64,64,96) f32, w_qkv:(96,288), pos:(7,7,7), w_out:(96,96), b_out:(96)
// R15: R14 + s_setprio(1) around phase-3/4 dependent cores (T5; de-phased
// wave regime matches m191's attn-positive case).

typedef __attribute__((ext_vector_type(8))) short bv8;     // 8 bf16 MFMA frag
typedef __attribute__((ext_vector_type(4))) float fv4;     // MFMA accumulator
typedef __attribute__((ext_vector_type(4))) unsigned uv4;  // 4 packed bf16x2

__device__ __forceinline__ unsigned short f2bf(float f) {
    union { __hip_bfloat16 h; unsigned short s; } v;
    v.h = __float2bfloat16(f);
    return v.s;
}

__device__ __forceinline__ unsigned pack2(float lo, float hi) {
    union { __hip_bfloat162 h; unsigned u; } v;
    v.h = __float22bfloat162_rn(make_float2(lo, hi));
    return v.u;
}

__device__ __forceinline__ bv8 cvt8(const float* __restrict__ p) {
    float4 a = *(const float4*)p;
    float4 b = *(const float4*)(p + 4);
    uv4 u;
    u[0] = pack2(a.x, a.y); u[1] = pack2(a.z, a.w);
    u[2] = pack2(b.x, b.y); u[3] = pack2(b.z, b.w);
    return __builtin_bit_cast(bv8, u);
}

// D-layout (q-on-columns) pair-packed tile pair -> A-fragment (verified R4-R14).
#define REBUILD(dst, lo, hi)  do {                                              \
    unsigned w0 = (unsigned)__shfl((int)(lo)[0], lsrc0, 64);                    \
    unsigned w1 = (unsigned)__shfl((int)(lo)[1], lsrc0, 64);                    \
    unsigned w2 = (unsigned)__shfl((int)(lo)[0], lsrc1, 64);                    \
    unsigned w3 = (unsigned)__shfl((int)(lo)[1], lsrc1, 64);                    \
    unsigned v0 = (unsigned)__shfl((int)(hi)[0], lsrc0, 64);                    \
    unsigned v1 = (unsigned)__shfl((int)(hi)[1], lsrc0, 64);                    \
    unsigned v2 = (unsigned)__shfl((int)(hi)[0], lsrc1, 64);                    \
    unsigned v3 = (unsigned)__shfl((int)(hi)[1], lsrc1, 64);                    \
    uv4 u_;                                                                     \
    u_[0] = selhi ? v0 : w0; u_[1] = selhi ? v1 : w1;                           \
    u_[2] = selhi ? v2 : w2; u_[3] = selhi ? v3 : w3;                           \
    dst = __builtin_bit_cast(bv8, u_);                                          \
} while (0)

// ---- prep: transpose weights to (N,K) bf16, transposed+log2e-scaled bias ----
__global__ void prep_kernel(const float* __restrict__ wqkv,
                            const float* __restrict__ wout,
                            const float* __restrict__ pos,
                            float* __restrict__ biasT,
                            unsigned short* __restrict__ wqT,
                            unsigned short* __restrict__ woT)
{
    int id = blockIdx.x * 256 + threadIdx.x;
    if (id < 27648) {                       // wqT[n][k] = w_qkv[k][n]
        int n = id / 96, k = id % 96;
        wqT[id] = f2bf(wqkv[k * 288 + n]);
    } else if (id < 36864) {                // woT[n][k] = w_out[k][n]
        int j = id - 27648;
        int n = j / 96, k = j % 96;
        woT[j] = f2bf(wout[k * 96 + n]);
    } else {                                // biasT[kj][qi] = pos[rel] * log2(e)
        int i = id - 36864;
        int kj = i >> 6, qi = i & 63;
        int dh = ((kj >> 4) & 3) - ((qi >> 4) & 3) + 3;
        int dw = ((kj >> 2) & 3) - ((qi >> 2) & 3) + 3;
        int dd = (kj & 3) - (qi & 3) + 3;
        biasT[kj * 64 + qi] = pos[(dh * 7 + dw) * 7 + dd] * 1.4426950408889634f;
    }
}

// ---- fused window attention: 1 block = 1 window, 4 waves, 40448 B LDS ----
__global__ void __launch_bounds__(256)
__attribute__((amdgpu_waves_per_eu(4, 4))) winattn_kernel(
    const float* __restrict__ x,
    const float* __restrict__ b_out,
    const float* __restrict__ biasT,
    const unsigned short* __restrict__ wqT,
    const unsigned short* __restrict__ woT,
    float* __restrict__ out)
{
    __shared__ __align__(16) unsigned short au[64 * 104];  // Q (shared) -> attn-out
    __shared__ __align__(16) unsigned short ks[64 * 104];  // K row-major
    __shared__ __align__(16) unsigned short vts[96 * 72];  // V^T [d][token]

    const int tid = threadIdx.x;
    const int w = tid >> 6, lane = tid & 63;
    const int c = lane & 15, g = lane >> 4;
    const int widx = blockIdx.x, bb = blockIdx.y;
    const int bh = (widx >> 8) & 15, bw2 = (widx >> 4) & 15, bd = widx & 15;

    const int ST_W = 64 * 96, ST_H = 64 * 64 * 96;
    const int xbase = ((bb * 64 + bh * 4) * 64 + bw2 * 4) * 64 * 96 + bd * 4 * 96;
    const int i0 = w * 16;

    const int lsrc0 = (((2 * g) & 3) << 4) + c;
    const int lsrc1 = (((2 * g + 1) & 3) << 4) + c;
    const bool selhi = (g & 2) != 0;

    // ---- A-fragments: ALL 64 tokens (4 strips) -> bf16 regs (48 VGPR) ----
    bv8 af[4][3];
#pragma unroll
    for (int mt = 0; mt < 4; ++mt) {
        const float* tp = x + xbase + mt * ST_H + ((c >> 2) & 3) * ST_W + (c & 3) * 96;
#pragma unroll
        for (int k = 0; k < 3; ++k)
            af[mt][k] = cvt8(tp + k * 32 + g * 8);
    }

    // ---- phase 2: QKV = X @ Wqkv, cooperative: all mt per wave, nt quarter ----
    const int ntbase = (w < 2) ? w * 5 : 10 + (w - 2) * 4;
    const int ntcnt  = (w < 2) ? 5 : 4;
    const unsigned short* bsrc = wqT + c * 96 + g * 8;
    bv8 b0[3], bn[3];
#pragma unroll
    for (int k = 0; k < 3; ++k) b0[k] = *(const bv8*)(bsrc + ntbase * 1536 + k * 32);

#pragma unroll 1
    for (int i = 0; i < ntcnt; ++i) {
        const int nt = ntbase + i;
        if (i + 1 < ntcnt) {
#pragma unroll
            for (int k = 0; k < 3; ++k) bn[k] = *(const bv8*)(bsrc + (nt + 1) * 1536 + k * 32);
        }
        fv4 acc[4];
#pragma unroll
        for (int mt = 0; mt < 4; ++mt) acc[mt] = (fv4){0.f, 0.f, 0.f, 0.f};
#pragma unroll
        for (int k = 0; k < 3; ++k)
#pragma unroll
            for (int mt = 0; mt < 4; ++mt)
                acc[mt] = __builtin_amdgcn_mfma_f32_16x16x32_bf16(af[mt][k], b0[k], acc[mt], 0, 0, 0);
#pragma unroll
        for (int mt = 0; mt < 4; ++mt) {
            int row = mt * 16 + 4 * g;
            if (nt < 6) {            // Q -> shared au [token][dim]
#pragma unroll
                for (int r = 0; r < 4; ++r)
                    au[(row + r) * 104 + nt * 16 + c] = f2bf(acc[mt][r]);
            } else if (nt < 12) {    // K -> shared ks [token][dim]
#pragma unroll
                for (int r = 0; r < 4; ++r)
                    ks[(row + r) * 104 + (nt - 6) * 16 + c] = f2bf(acc[mt][r]);
            } else {                 // V -> transposed [d][token], packed writes
                int d = (nt - 12) * 16 + c;
                *(unsigned*)&vts[d * 72 + row]     = pack2(acc[mt][0], acc[mt][1]);
                *(unsigned*)&vts[d * 72 + row + 2] = pack2(acc[mt][2], acc[mt][3]);
            }
        }
        if (i + 1 < ntcnt) {
#pragma unroll
            for (int k = 0; k < 3; ++k) b0[k] = bn[k];
        }
    }
    __syncthreads();   // Q,K,V visibility — the only barrier

    // bias rows (transposed table, coalesced across c), log2e pre-folded
    float brow[4][4];
#pragma unroll
    for (int nt = 0; nt < 4; ++nt)
#pragma unroll
        for (int r = 0; r < 4; ++r)
            brow[nt][r] = biasT[(nt * 16 + 4 * g + r) * 64 + i0 + c];

    // ---- phase 3: head-serial; waves de-phased -> setprio pays (T5/m191) ----
    const float scale2 = 0.17677669529663687f * 1.4426950408889634f; // scale*log2e

#pragma unroll 1
    for (int h = 0; h < 3; ++h) {
        // qf re-loaded per head from LDS (no runtime-indexed reg array; rule #20)
        bv8 qf = *(const bv8*)&au[(i0 + c) * 104 + h * 32 + g * 8];
        bv8 kf[4];
#pragma unroll
        for (int nt = 0; nt < 4; ++nt)
            kf[nt] = *(const bv8*)&ks[(nt * 16 + c) * 104 + h * 32 + g * 8];

        __builtin_amdgcn_s_setprio(1);   // own the issue slots through the core
        float sv[4][4];
#pragma unroll
        for (int nt = 0; nt < 4; ++nt) {
            fv4 z = {0.f, 0.f, 0.f, 0.f};
            fv4 s = __builtin_amdgcn_mfma_f32_16x16x32_bf16(kf[nt], qf, z, 0, 0, 0);
#pragma unroll
            for (int r = 0; r < 4; ++r)
                sv[nt][r] = s[r] * scale2 + brow[nt][r];
        }
        // softmax (no max-subtraction: args bounded; verified R6-R14)
        float sm = 0.f;
#pragma unroll
        for (int nt = 0; nt < 4; ++nt)
#pragma unroll
            for (int r = 0; r < 4; ++r) {
                float e = exp2f(sv[nt][r]);
                sv[nt][r] = e;
                sm += e;
            }
        sm += __shfl_xor(sm, 16, 64);
        sm += __shfl_xor(sm, 32, 64);
        float inv = __builtin_amdgcn_rcpf(sm);

        unsigned pk[4][2];
#pragma unroll
        for (int nt = 0; nt < 4; ++nt) {
            pk[nt][0] = pack2(sv[nt][0] * inv, sv[nt][1] * inv);
            pk[nt][1] = pack2(sv[nt][2] * inv, sv[nt][3] * inv);
        }
        bv8 pf[2];
#pragma unroll
        for (int k2 = 0; k2 < 2; ++k2)
            REBUILD(pf[k2], pk[2 * k2], pk[2 * k2 + 1]);

        // O strip = P @ V -> au overlay (own rows)
#pragma unroll
        for (int dt = 0; dt < 2; ++dt) {
            fv4 oacc = {0.f, 0.f, 0.f, 0.f};
#pragma unroll
            for (int k2 = 0; k2 < 2; ++k2) {
                bv8 vf = *(const bv8*)&vts[(h * 32 + dt * 16 + c) * 72 + k2 * 32 + g * 8];
                oacc = __builtin_amdgcn_mfma_f32_16x16x32_bf16(pf[k2], vf, oacc, 0, 0, 0);
            }
#pragma unroll
            for (int r = 0; r < 4; ++r)
                au[(i0 + 4 * g + r) * 104 + h * 32 + dt * 16 + c] = f2bf(oacc[r]);
        }
        __builtin_amdgcn_s_setprio(0);   // release between heads
    }

    // ---- phase 4: out = A @ Wout + b on own strip (no barrier needed) ----
    bv8 afo[3];
#pragma unroll
    for (int k = 0; k < 3; ++k)
        afo[k] = *(const bv8*)&au[(i0 + c) * 104 + k * 32 + g * 8];

    const unsigned short* osrc = woT + c * 96 + g * 8;
    bv8 ob0[3], obn[3];
#pragma unroll
    for (int k = 0; k < 3; ++k) ob0[k] = *(const bv8*)(osrc + k * 32);

#pragma unroll 1
    for (int nt = 0; nt < 6; ++nt) {
        if (nt < 5) {
#pragma unroll
            for (int k = 0; k < 3; ++k) obn[k] = *(const bv8*)(osrc + (nt + 1) * 1536 + k * 32);
        }
        __builtin_amdgcn_s_setprio(1);
        fv4 acc = {0.f, 0.f, 0.f, 0.f};
#pragma unroll
        for (int k = 0; k < 3; ++k)
            acc = __builtin_amdgcn_mfma_f32_16x16x32_bf16(afo[k], ob0[k], acc, 0, 0, 0);
        __builtin_amdgcn_s_setprio(0);
        int cc = nt * 16 + c;
        float bo = b_out[cc];
#pragma unroll
        for (int r = 0; r < 4; ++r) {
            int t = i0 + 4 * g + r;
            out[xbase + (t >> 4) * ST_H + ((t >> 2) & 3) * ST_W + (t & 3) * 96 + cc] = acc[r] + bo;
        }
        if (nt < 5) {
#pragma unroll
            for (int k = 0; k < 3; ++k) ob0[k] = obn[k];
        }
    }
}

extern "C" void kernel_launch(void* const* d_in, const int* in_sizes, int n_in,
                              void* d_out, int out_size, void* d_ws, size_t ws_size,
                              hipStream_t stream)
{
    const float* x    = (const float*)d_in[0];
    const float* wqkv = (const float*)d_in[1];
    const float* pos  = (const float*)d_in[2];
    const float* wout = (const float*)d_in[3];
    const float* bout = (const float*)d_in[4];
    float* out = (float*)d_out;

    float* biasT = (float*)d_ws;
    unsigned short* wqT = (unsigned short*)((char*)d_ws + 16384);
    unsigned short* woT = (unsigned short*)((char*)d_ws + 16384 + 55296);

    prep_kernel<<<160, 256, 0, stream>>>(wqkv, wout, pos, biasT, wqT, woT);
    winattn_kernel<<<dim3(4096, 2), 256, 0, stream>>>(x, bout, biasT, wqT, woT, out);
}

// Round 16
// 171.640 us; speedup vs baseline: 1.1247x; 1.1247x over previous
//
#include <hip/hip_runtime.h>
#include <hip/hip_bf16.h>

// 3D window attention (Swin-style), fully fused per 4x4x4 window.
// x:(2,64,64,64,96) f32, w_qkv:(96,288), pos:(7,7,7), w_out:(96,96), b_out:(96)
// R16: R14 base + nontemporal out stores (out never re-read; stop evicting x
// from L3 between replays -> cheaper x prologue loads).

typedef __attribute__((ext_vector_type(8))) short bv8;     // 8 bf16 MFMA frag
typedef __attribute__((ext_vector_type(4))) float fv4;     // MFMA accumulator
typedef __attribute__((ext_vector_type(4))) unsigned uv4;  // 4 packed bf16x2

__device__ __forceinline__ unsigned short f2bf(float f) {
    union { __hip_bfloat16 h; unsigned short s; } v;
    v.h = __float2bfloat16(f);
    return v.s;
}

__device__ __forceinline__ unsigned pack2(float lo, float hi) {
    union { __hip_bfloat162 h; unsigned u; } v;
    v.h = __float22bfloat162_rn(make_float2(lo, hi));
    return v.u;
}

__device__ __forceinline__ bv8 cvt8(const float* __restrict__ p) {
    float4 a = *(const float4*)p;
    float4 b = *(const float4*)(p + 4);
    uv4 u;
    u[0] = pack2(a.x, a.y); u[1] = pack2(a.z, a.w);
    u[2] = pack2(b.x, b.y); u[3] = pack2(b.z, b.w);
    return __builtin_bit_cast(bv8, u);
}

// D-layout (q-on-columns) pair-packed tile pair -> A-fragment (verified R4-R15).
#define REBUILD(dst, lo, hi)  do {                                              \
    unsigned w0 = (unsigned)__shfl((int)(lo)[0], lsrc0, 64);                    \
    unsigned w1 = (unsigned)__shfl((int)(lo)[1], lsrc0, 64);                    \
    unsigned w2 = (unsigned)__shfl((int)(lo)[0], lsrc1, 64);                    \
    unsigned w3 = (unsigned)__shfl((int)(lo)[1], lsrc1, 64);                    \
    unsigned v0 = (unsigned)__shfl((int)(hi)[0], lsrc0, 64);                    \
    unsigned v1 = (unsigned)__shfl((int)(hi)[1], lsrc0, 64);                    \
    unsigned v2 = (unsigned)__shfl((int)(hi)[0], lsrc1, 64);                    \
    unsigned v3 = (unsigned)__shfl((int)(hi)[1], lsrc1, 64);                    \
    uv4 u_;                                                                     \
    u_[0] = selhi ? v0 : w0; u_[1] = selhi ? v1 : w1;                           \
    u_[2] = selhi ? v2 : w2; u_[3] = selhi ? v3 : w3;                           \
    dst = __builtin_bit_cast(bv8, u_);                                          \
} while (0)

// ---- prep: transpose weights to (N,K) bf16, transposed+log2e-scaled bias ----
__global__ void prep_kernel(const float* __restrict__ wqkv,
                            const float* __restrict__ wout,
                            const float* __restrict__ pos,
                            float* __restrict__ biasT,
                            unsigned short* __restrict__ wqT,
                            unsigned short* __restrict__ woT)
{
    int id = blockIdx.x * 256 + threadIdx.x;
    if (id < 27648) {                       // wqT[n][k] = w_qkv[k][n]
        int n = id / 96, k = id % 96;
        wqT[id] = f2bf(wqkv[k * 288 + n]);
    } else if (id < 36864) {                // woT[n][k] = w_out[k][n]
        int j = id - 27648;
        int n = j / 96, k = j % 96;
        woT[j] = f2bf(wout[k * 96 + n]);
    } else {                                // biasT[kj][qi] = pos[rel] * log2(e)
        int i = id - 36864;
        int kj = i >> 6, qi = i & 63;
        int dh = ((kj >> 4) & 3) - ((qi >> 4) & 3) + 3;
        int dw = ((kj >> 2) & 3) - ((qi >> 2) & 3) + 3;
        int dd = (kj & 3) - (qi & 3) + 3;
        biasT[kj * 64 + qi] = pos[(dh * 7 + dw) * 7 + dd] * 1.4426950408889634f;
    }
}

// ---- fused window attention: 1 block = 1 window, 4 waves, 40448 B LDS ----
__global__ void __launch_bounds__(256)
__attribute__((amdgpu_waves_per_eu(4, 4))) winattn_kernel(
    const float* __restrict__ x,
    const float* __restrict__ b_out,
    const float* __restrict__ biasT,
    const unsigned short* __restrict__ wqT,
    const unsigned short* __restrict__ woT,
    float* __restrict__ out)
{
    __shared__ __align__(16) unsigned short au[64 * 104];  // Q (shared) -> attn-out
    __shared__ __align__(16) unsigned short ks[64 * 104];  // K row-major
    __shared__ __align__(16) unsigned short vts[96 * 72];  // V^T [d][token]

    const int tid = threadIdx.x;
    const int w = tid >> 6, lane = tid & 63;
    const int c = lane & 15, g = lane >> 4;
    const int widx = blockIdx.x, bb = blockIdx.y;
    const int bh = (widx >> 8) & 15, bw2 = (widx >> 4) & 15, bd = widx & 15;

    const int ST_W = 64 * 96, ST_H = 64 * 64 * 96;
    const int xbase = ((bb * 64 + bh * 4) * 64 + bw2 * 4) * 64 * 96 + bd * 4 * 96;
    const int i0 = w * 16;

    const int lsrc0 = (((2 * g) & 3) << 4) + c;
    const int lsrc1 = (((2 * g + 1) & 3) << 4) + c;
    const bool selhi = (g & 2) != 0;

    // ---- A-fragments: ALL 64 tokens (4 strips) -> bf16 regs (48 VGPR) ----
    bv8 af[4][3];
#pragma unroll
    for (int mt = 0; mt < 4; ++mt) {
        const float* tp = x + xbase + mt * ST_H + ((c >> 2) & 3) * ST_W + (c & 3) * 96;
#pragma unroll
        for (int k = 0; k < 3; ++k)
            af[mt][k] = cvt8(tp + k * 32 + g * 8);
    }

    // ---- phase 2: QKV = X @ Wqkv, cooperative: all mt per wave, nt quarter ----
    const int ntbase = (w < 2) ? w * 5 : 10 + (w - 2) * 4;
    const int ntcnt  = (w < 2) ? 5 : 4;
    const unsigned short* bsrc = wqT + c * 96 + g * 8;
    bv8 b0[3], bn[3];
#pragma unroll
    for (int k = 0; k < 3; ++k) b0[k] = *(const bv8*)(bsrc + ntbase * 1536 + k * 32);

#pragma unroll 1
    for (int i = 0; i < ntcnt; ++i) {
        const int nt = ntbase + i;
        if (i + 1 < ntcnt) {
#pragma unroll
            for (int k = 0; k < 3; ++k) bn[k] = *(const bv8*)(bsrc + (nt + 1) * 1536 + k * 32);
        }
        fv4 acc[4];
#pragma unroll
        for (int mt = 0; mt < 4; ++mt) acc[mt] = (fv4){0.f, 0.f, 0.f, 0.f};
#pragma unroll
        for (int k = 0; k < 3; ++k)
#pragma unroll
            for (int mt = 0; mt < 4; ++mt)
                acc[mt] = __builtin_amdgcn_mfma_f32_16x16x32_bf16(af[mt][k], b0[k], acc[mt], 0, 0, 0);
#pragma unroll
        for (int mt = 0; mt < 4; ++mt) {
            int row = mt * 16 + 4 * g;
            if (nt < 6) {            // Q -> shared au [token][dim]
#pragma unroll
                for (int r = 0; r < 4; ++r)
                    au[(row + r) * 104 + nt * 16 + c] = f2bf(acc[mt][r]);
            } else if (nt < 12) {    // K -> shared ks [token][dim]
#pragma unroll
                for (int r = 0; r < 4; ++r)
                    ks[(row + r) * 104 + (nt - 6) * 16 + c] = f2bf(acc[mt][r]);
            } else {                 // V -> transposed [d][token], packed writes
                int d = (nt - 12) * 16 + c;
                *(unsigned*)&vts[d * 72 + row]     = pack2(acc[mt][0], acc[mt][1]);
                *(unsigned*)&vts[d * 72 + row + 2] = pack2(acc[mt][2], acc[mt][3]);
            }
        }
        if (i + 1 < ntcnt) {
#pragma unroll
            for (int k = 0; k < 3; ++k) b0[k] = bn[k];
        }
    }
    __syncthreads();   // Q,K,V visibility — the only barrier

    // bias rows (transposed table, coalesced across c), log2e pre-folded
    float brow[4][4];
#pragma unroll
    for (int nt = 0; nt < 4; ++nt)
#pragma unroll
        for (int r = 0; r < 4; ++r)
            brow[nt][r] = biasT[(nt * 16 + 4 * g + r) * 64 + i0 + c];

    // ---- phase 3: head-serial, small body; wave owns q-rows i0..i0+15 ----
    const float scale2 = 0.17677669529663687f * 1.4426950408889634f; // scale*log2e

#pragma unroll 1
    for (int h = 0; h < 3; ++h) {
        // qf re-loaded per head from LDS (no runtime-indexed reg array; rule #20)
        bv8 qf = *(const bv8*)&au[(i0 + c) * 104 + h * 32 + g * 8];
        bv8 kf[4];
#pragma unroll
        for (int nt = 0; nt < 4; ++nt)
            kf[nt] = *(const bv8*)&ks[(nt * 16 + c) * 104 + h * 32 + g * 8];
        float sv[4][4];
#pragma unroll
        for (int nt = 0; nt < 4; ++nt) {
            fv4 z = {0.f, 0.f, 0.f, 0.f};
            fv4 s = __builtin_amdgcn_mfma_f32_16x16x32_bf16(kf[nt], qf, z, 0, 0, 0);
#pragma unroll
            for (int r = 0; r < 4; ++r)
                sv[nt][r] = s[r] * scale2 + brow[nt][r];
        }
        // softmax (no max-subtraction: args bounded; verified R6-R15)
        float sm = 0.f;
#pragma unroll
        for (int nt = 0; nt < 4; ++nt)
#pragma unroll
            for (int r = 0; r < 4; ++r) {
                float e = exp2f(sv[nt][r]);
                sv[nt][r] = e;
                sm += e;
            }
        sm += __shfl_xor(sm, 16, 64);
        sm += __shfl_xor(sm, 32, 64);
        float inv = __builtin_amdgcn_rcpf(sm);

        unsigned pk[4][2];
#pragma unroll
        for (int nt = 0; nt < 4; ++nt) {
            pk[nt][0] = pack2(sv[nt][0] * inv, sv[nt][1] * inv);
            pk[nt][1] = pack2(sv[nt][2] * inv, sv[nt][3] * inv);
        }
        bv8 pf[2];
#pragma unroll
        for (int k2 = 0; k2 < 2; ++k2)
            REBUILD(pf[k2], pk[2 * k2], pk[2 * k2 + 1]);

        // O strip = P @ V -> au overlay (own rows)
#pragma unroll
        for (int dt = 0; dt < 2; ++dt) {
            fv4 oacc = {0.f, 0.f, 0.f, 0.f};
#pragma unroll
            for (int k2 = 0; k2 < 2; ++k2) {
                bv8 vf = *(const bv8*)&vts[(h * 32 + dt * 16 + c) * 72 + k2 * 32 + g * 8];
                oacc = __builtin_amdgcn_mfma_f32_16x16x32_bf16(pf[k2], vf, oacc, 0, 0, 0);
            }
#pragma unroll
            for (int r = 0; r < 4; ++r)
                au[(i0 + 4 * g + r) * 104 + h * 32 + dt * 16 + c] = f2bf(oacc[r]);
        }
    }

    // ---- phase 4: out = A @ Wout + b on own strip (no barrier needed) ----
    bv8 afo[3];
#pragma unroll
    for (int k = 0; k < 3; ++k)
        afo[k] = *(const bv8*)&au[(i0 + c) * 104 + k * 32 + g * 8];

    const unsigned short* osrc = woT + c * 96 + g * 8;
    bv8 ob0[3], obn[3];
#pragma unroll
    for (int k = 0; k < 3; ++k) ob0[k] = *(const bv8*)(osrc + k * 32);

#pragma unroll 1
    for (int nt = 0; nt < 6; ++nt) {
        if (nt < 5) {
#pragma unroll
            for (int k = 0; k < 3; ++k) obn[k] = *(const bv8*)(osrc + (nt + 1) * 1536 + k * 32);
        }
        fv4 acc = {0.f, 0.f, 0.f, 0.f};
#pragma unroll
        for (int k = 0; k < 3; ++k)
            acc = __builtin_amdgcn_mfma_f32_16x16x32_bf16(afo[k], ob0[k], acc, 0, 0, 0);
        int cc = nt * 16 + c;
        float bo = b_out[cc];
#pragma unroll
        for (int r = 0; r < 4; ++r) {
            int t = i0 + 4 * g + r;
            // nontemporal: out is write-once, never re-read -> don't pollute L2/L3
            __builtin_nontemporal_store(acc[r] + bo,
                out + xbase + (t >> 4) * ST_H + ((t >> 2) & 3) * ST_W + (t & 3) * 96 + cc);
        }
        if (nt < 5) {
#pragma unroll
            for (int k = 0; k < 3; ++k) ob0[k] = obn[k];
        }
    }
}

extern "C" void kernel_launch(void* const* d_in, const int* in_sizes, int n_in,
                              void* d_out, int out_size, void* d_ws, size_t ws_size,
                              hipStream_t stream)
{
    const float* x    = (const float*)d_in[0];
    const float* wqkv = (const float*)d_in[1];
    const float* pos  = (const float*)d_in[2];
    const float* wout = (const float*)d_in[3];
    const float* bout = (const float*)d_in[4];
    float* out = (float*)d_out;

    float* biasT = (float*)d_ws;
    unsigned short* wqT = (unsigned short*)((char*)d_ws + 16384);
    unsigned short* woT = (unsigned short*)((char*)d_ws + 16384 + 55296);

    prep_kernel<<<160, 256, 0, stream>>>(wqkv, wout, pos, biasT, wqT, woT);
    winattn_kernel<<<dim3(4096, 2), 256, 0, stream>>>(x, bout, biasT, wqT, woT, out);
}